// Round 2
// baseline (3177.250 us; speedup 1.0000x reference)
//
#include <hip/hip_runtime.h>
#include <hip/hip_bf16.h>
#include <math.h>

#define H_DIM 2048
#define N_ST 8
#define B_SZ 4
#define L_SEQ 4096
#define DMODEL 1024
#define DCONV 4
#define CL 128
#define NC (L_SEQ / CL)   // 32

// -------- per-batch workspace layout (floats), total ~18.2M floats = 73 MB --------
// xz_b   : [2H][L]      = 16,777,216  @ 0            (x rows 0..H-1, z rows H..2H-1)
// coef   : 6 * [H][N]   =     98,304  @ 16,777,216
// states : [H][NC][N][2]=  1,048,576  @ 16,875,520
// look   : [H][NC][4]   =    262,144  @ 17,924,096   (conv lookback x[-3..-1], pad)
// y aliases the x half of xz (phase3 writes in place).
#define WS_XZ     0
#define WS_COEF   16777216
#define WS_STATES 16875520
#define WS_LOOK   17924096

// ============ coefficient precompute ============
__global__ void coef_kernel(const float* __restrict__ log_dt,
                            const float* __restrict__ log_A_real,
                            const float* __restrict__ A_imag,
                            const float* __restrict__ C_re,
                            const float* __restrict__ C_im,
                            float* __restrict__ coef) {
    int i = blockIdx.x * blockDim.x + threadIdx.x;
    if (i >= H_DIM * N_ST) return;
    int h = i >> 3;
    float dt = expf(log_dt[h]);
    float Ar = -expf(log_A_real[i]);
    float Ai = A_imag[i];
    // w = exp(dt*A)
    float er = expf(dt * Ar);
    float ang = dt * Ai;
    float wr = er * cosf(ang);
    float wi = er * sinf(ang);
    // Ct = C * (w - 1) / A
    float den = Ar * Ar + Ai * Ai;
    float qr = ((wr - 1.f) * Ar + wi * Ai) / den;
    float qi = (wi * Ar - (wr - 1.f) * Ai) / den;
    float Cr = C_re[i], Ci = C_im[i];
    float Ctr = Cr * qr - Ci * qi;
    float Cti = Cr * qi + Ci * qr;
    // p = w^CL = exp(CL*dt*A)
    float eCL = expf((float)CL * dt * Ar);
    float aCL = (float)CL * dt * Ai;
    float pr = eCL * cosf(aCL);
    float pi = eCL * sinf(aCL);
    const int HN = H_DIM * N_ST;
    coef[i]          = wr;
    coef[HN + i]     = wi;
    coef[2 * HN + i] = Ctr;
    coef[3 * HN + i] = Cti;
    coef[4 * HN + i] = pr;
    coef[5 * HN + i] = pi;
}

// ============ in_proj GEMM (one batch): xz[e,l] = sum_d W_in[e,d]*hid_b[l,d] ============
// grid: (L/128, 2H/128), 256 threads, 128x128 tile, 8x8 micro
__global__ __launch_bounds__(256) void gemm_in(const float* __restrict__ hid_b,
                                               const float* __restrict__ W,
                                               float* __restrict__ xz) {
    __shared__ float As[16][132];  // [d][e]
    __shared__ float Bs[16][132];  // [d][l]
    const int tid = threadIdx.x;
    const int tx = tid & 15, ty = tid >> 4;
    const int bx = blockIdx.x, by = blockIdx.y;

    const float* Ablk = W + (size_t)(by * 128) * DMODEL;
    const float* Bblk = hid_b + (size_t)(bx * 128) * DMODEL;

    const int lr = tid >> 2;          // 0..63
    const int lc = (tid & 3) << 2;    // 0,4,8,12

    float acc[8][8];
#pragma unroll
    for (int i = 0; i < 8; ++i)
#pragma unroll
        for (int j = 0; j < 8; ++j) acc[i][j] = 0.f;

    for (int kt = 0; kt < DMODEL; kt += 16) {
        float4 a0 = *(const float4*)(Ablk + (size_t)lr * DMODEL + kt + lc);
        float4 a1 = *(const float4*)(Ablk + (size_t)(lr + 64) * DMODEL + kt + lc);
        float4 b0 = *(const float4*)(Bblk + (size_t)lr * DMODEL + kt + lc);
        float4 b1 = *(const float4*)(Bblk + (size_t)(lr + 64) * DMODEL + kt + lc);
        __syncthreads();
        As[lc + 0][lr] = a0.x; As[lc + 1][lr] = a0.y; As[lc + 2][lr] = a0.z; As[lc + 3][lr] = a0.w;
        As[lc + 0][lr + 64] = a1.x; As[lc + 1][lr + 64] = a1.y; As[lc + 2][lr + 64] = a1.z; As[lc + 3][lr + 64] = a1.w;
        Bs[lc + 0][lr] = b0.x; Bs[lc + 1][lr] = b0.y; Bs[lc + 2][lr] = b0.z; Bs[lc + 3][lr] = b0.w;
        Bs[lc + 0][lr + 64] = b1.x; Bs[lc + 1][lr + 64] = b1.y; Bs[lc + 2][lr + 64] = b1.z; Bs[lc + 3][lr + 64] = b1.w;
        __syncthreads();
#pragma unroll
        for (int d = 0; d < 16; ++d) {
            float ar[8], br[8];
            *(float4*)(ar)     = *(const float4*)&As[d][ty * 4];
            *(float4*)(ar + 4) = *(const float4*)&As[d][ty * 4 + 64];
            *(float4*)(br)     = *(const float4*)&Bs[d][tx * 4];
            *(float4*)(br + 4) = *(const float4*)&Bs[d][tx * 4 + 64];
#pragma unroll
            for (int i = 0; i < 8; ++i)
#pragma unroll
                for (int j = 0; j < 8; ++j) acc[i][j] += ar[i] * br[j];
        }
    }

    float* Cb = xz + (size_t)(by * 128) * L_SEQ + bx * 128;
#pragma unroll
    for (int i = 0; i < 8; ++i) {
        int e = ty * 4 + ((i < 4) ? i : 64 + i - 4);
        float4 v0 = make_float4(acc[i][0], acc[i][1], acc[i][2], acc[i][3]);
        float4 v1 = make_float4(acc[i][4], acc[i][5], acc[i][6], acc[i][7]);
        *(float4*)(Cb + (size_t)e * L_SEQ + tx * 4) = v0;
        *(float4*)(Cb + (size_t)e * L_SEQ + tx * 4 + 64) = v1;
    }
}

// ============ scan phase 1: local chunk scans (fused conv+SiLU), save states + lookback ============
__global__ __launch_bounds__(256) void scan_phase1(const float* __restrict__ xz,
                                                   const float* __restrict__ coef,
                                                   const float* __restrict__ conv_w,
                                                   const float* __restrict__ conv_b,
                                                   float* __restrict__ states,
                                                   float* __restrict__ look) {
    int t = blockIdx.x * 256 + threadIdx.x;   // t = h*NC + c, over H*NC = 65536
    int c = t & (NC - 1);
    int h = t >> 5;

    const int HN = H_DIM * N_ST;
    float wr[N_ST], wi[N_ST];
#pragma unroll
    for (int n = 0; n < N_ST; ++n) {
        wr[n] = coef[h * N_ST + n];
        wi[n] = coef[HN + h * N_ST + n];
    }
    float cw0 = conv_w[h * 4 + 0], cw1 = conv_w[h * 4 + 1];
    float cw2 = conv_w[h * 4 + 2], cw3 = conv_w[h * 4 + 3];
    float cb = conv_b[h];

    const float* xrow = xz + (size_t)h * L_SEQ + c * CL;
    float x3 = 0.f, x2 = 0.f, x1 = 0.f;
    if (c > 0) {
        float4 p = *(const float4*)(xrow - 4);
        x3 = p.y; x2 = p.z; x1 = p.w;
    }
    // save conv lookback for phase3 (which writes y over x in place)
    *(float4*)(look + (size_t)t * 4) = make_float4(x3, x2, x1, 0.f);

    float sr[N_ST], si[N_ST];
#pragma unroll
    for (int n = 0; n < N_ST; ++n) { sr[n] = 0.f; si[n] = 0.f; }

    for (int j = 0; j < CL; j += 4) {
        float4 v = *(const float4*)(xrow + j);
        float xv[4] = {v.x, v.y, v.z, v.w};
#pragma unroll
        for (int k = 0; k < 4; ++k) {
            float u = cw0 * x3 + cw1 * x2 + cw2 * x1 + cw3 * xv[k] + cb;
            float xc = u / (1.f + __expf(-u));
            x3 = x2; x2 = x1; x1 = xv[k];
#pragma unroll
            for (int n = 0; n < N_ST; ++n) {
                float nr = wr[n] * sr[n] - wi[n] * si[n] + xc;
                float ni = wr[n] * si[n] + wi[n] * sr[n];
                sr[n] = nr; si[n] = ni;
            }
        }
    }
    float* st = states + (size_t)t * (N_ST * 2);
#pragma unroll
    for (int n = 0; n < N_ST; ++n) { st[2 * n] = sr[n]; st[2 * n + 1] = si[n]; }
}

// ============ scan phase 2: combine chunk states -> chunk init states ============
__global__ __launch_bounds__(256) void scan_phase2(const float* __restrict__ coef,
                                                   float* __restrict__ states) {
    int h = blockIdx.x * 256 + threadIdx.x;   // over H
    if (h >= H_DIM) return;
    const int HN = H_DIM * N_ST;
    float pr[N_ST], pi[N_ST];
#pragma unroll
    for (int n = 0; n < N_ST; ++n) {
        pr[n] = coef[4 * HN + h * N_ST + n];
        pi[n] = coef[5 * HN + h * N_ST + n];
    }
    float sr[N_ST], si[N_ST];
#pragma unroll
    for (int n = 0; n < N_ST; ++n) { sr[n] = 0.f; si[n] = 0.f; }
    float* base = states + (size_t)h * NC * (N_ST * 2);
    for (int c = 0; c < NC; ++c) {
        float* st = base + c * (N_ST * 2);
#pragma unroll
        for (int n = 0; n < N_ST; ++n) {
            float lr = st[2 * n], li = st[2 * n + 1];
            st[2 * n] = sr[n]; st[2 * n + 1] = si[n];  // init state for chunk c
            float nr = pr[n] * sr[n] - pi[n] * si[n] + lr;
            float ni = pr[n] * si[n] + pi[n] * sr[n] + li;
            sr[n] = nr; si[n] = ni;
        }
    }
}

// ============ scan phase 3: replay with init, fused D-skip + gate; writes y OVER x (alias) ============
__global__ __launch_bounds__(256) void scan_phase3(float* __restrict__ xz,
                                                   const float* __restrict__ coef,
                                                   const float* __restrict__ conv_w,
                                                   const float* __restrict__ conv_b,
                                                   const float* __restrict__ Dvec,
                                                   const float* __restrict__ states,
                                                   const float* __restrict__ look) {
    int t = blockIdx.x * 256 + threadIdx.x;   // t = h*NC + c
    int c = t & (NC - 1);
    int h = t >> 5;

    const int HN = H_DIM * N_ST;
    float wr[N_ST], wi[N_ST], Ctr[N_ST], Cti[N_ST];
#pragma unroll
    for (int n = 0; n < N_ST; ++n) {
        wr[n]  = coef[h * N_ST + n];
        wi[n]  = coef[HN + h * N_ST + n];
        Ctr[n] = coef[2 * HN + h * N_ST + n];
        Cti[n] = coef[3 * HN + h * N_ST + n];
    }
    float cw0 = conv_w[h * 4 + 0], cw1 = conv_w[h * 4 + 1];
    float cw2 = conv_w[h * 4 + 2], cw3 = conv_w[h * 4 + 3];
    float cb = conv_b[h];
    float Dh = Dvec[h];

    float* xrow = xz + (size_t)h * L_SEQ + c * CL;               // read x, write y in place
    const float* zrow = xz + (size_t)(H_DIM + h) * L_SEQ + c * CL;

    float4 lk = *(const float4*)(look + (size_t)t * 4);
    float x3 = lk.x, x2 = lk.y, x1 = lk.z;

    const float* st = states + (size_t)t * (N_ST * 2);
    float sr[N_ST], si[N_ST];
#pragma unroll
    for (int n = 0; n < N_ST; ++n) { sr[n] = st[2 * n]; si[n] = st[2 * n + 1]; }

    for (int j = 0; j < CL; j += 4) {
        float4 v = *(const float4*)(xrow + j);
        float4 zv = *(const float4*)(zrow + j);
        float xv[4] = {v.x, v.y, v.z, v.w};
        float zz[4] = {zv.x, zv.y, zv.z, zv.w};
        float out[4];
#pragma unroll
        for (int k = 0; k < 4; ++k) {
            float u = cw0 * x3 + cw1 * x2 + cw2 * x1 + cw3 * xv[k] + cb;
            float xc = u / (1.f + __expf(-u));
            x3 = x2; x2 = x1; x1 = xv[k];
            float accy = 0.f;
#pragma unroll
            for (int n = 0; n < N_ST; ++n) {
                float nr = wr[n] * sr[n] - wi[n] * si[n] + xc;
                float ni = wr[n] * si[n] + wi[n] * sr[n];
                sr[n] = nr; si[n] = ni;
                accy += Ctr[n] * nr - Cti[n] * ni;
            }
            float yv = 2.f * accy + Dh * xc;
            float g = zz[k] / (1.f + __expf(-zz[k]));
            out[k] = yv * g;
        }
        *(float4*)(xrow + j) = make_float4(out[0], out[1], out[2], out[3]);
    }
}

// ============ out_proj GEMM (one batch): out_b[l,m] = sum_h y[h,l]*W_out[m,h] ============
// grid: (DM/128, L/128)
__global__ __launch_bounds__(256) void gemm_out(const float* __restrict__ ybuf,
                                                const float* __restrict__ Wout,
                                                float* __restrict__ out_b) {
    __shared__ float Ys[16][132];  // [h][l]
    __shared__ float Ws[16][132];  // [h][m]
    const int tid = threadIdx.x;
    const int tx = tid & 15, ty = tid >> 4;
    const int bx = blockIdx.x;  // m tile
    const int by = blockIdx.y;  // l tile

    const float* Wblk = Wout + (size_t)(bx * 128) * H_DIM;
    const float* Yblk = ybuf + by * 128;

    const int lr = tid >> 2;
    const int lc = (tid & 3) << 2;
    const int yrow0 = tid >> 5;          // 0..7
    const int yc4 = (tid & 31) << 2;     // 0..124

    float acc[8][8];
#pragma unroll
    for (int i = 0; i < 8; ++i)
#pragma unroll
        for (int j = 0; j < 8; ++j) acc[i][j] = 0.f;

    for (int kt = 0; kt < H_DIM; kt += 16) {
        float4 w0 = *(const float4*)(Wblk + (size_t)lr * H_DIM + kt + lc);
        float4 w1 = *(const float4*)(Wblk + (size_t)(lr + 64) * H_DIM + kt + lc);
        float4 y0 = *(const float4*)(Yblk + (size_t)(kt + yrow0) * L_SEQ + yc4);
        float4 y1 = *(const float4*)(Yblk + (size_t)(kt + yrow0 + 8) * L_SEQ + yc4);
        __syncthreads();
        Ws[lc + 0][lr] = w0.x; Ws[lc + 1][lr] = w0.y; Ws[lc + 2][lr] = w0.z; Ws[lc + 3][lr] = w0.w;
        Ws[lc + 0][lr + 64] = w1.x; Ws[lc + 1][lr + 64] = w1.y; Ws[lc + 2][lr + 64] = w1.z; Ws[lc + 3][lr + 64] = w1.w;
        *(float4*)&Ys[yrow0][yc4] = y0;
        *(float4*)&Ys[yrow0 + 8][yc4] = y1;
        __syncthreads();
#pragma unroll
        for (int d = 0; d < 16; ++d) {
            float ar[8], br[8];
            *(float4*)(ar)     = *(const float4*)&Ys[d][ty * 4];        // l
            *(float4*)(ar + 4) = *(const float4*)&Ys[d][ty * 4 + 64];
            *(float4*)(br)     = *(const float4*)&Ws[d][tx * 4];        // m
            *(float4*)(br + 4) = *(const float4*)&Ws[d][tx * 4 + 64];
#pragma unroll
            for (int i = 0; i < 8; ++i)
#pragma unroll
                for (int j = 0; j < 8; ++j) acc[i][j] += ar[i] * br[j];
        }
    }

    float* Cb = out_b + (size_t)(by * 128) * DMODEL + bx * 128;
#pragma unroll
    for (int i = 0; i < 8; ++i) {
        int l = ty * 4 + ((i < 4) ? i : 64 + i - 4);
        float4 v0 = make_float4(acc[i][0], acc[i][1], acc[i][2], acc[i][3]);
        float4 v1 = make_float4(acc[i][4], acc[i][5], acc[i][6], acc[i][7]);
        *(float4*)(Cb + (size_t)l * DMODEL + tx * 4) = v0;
        *(float4*)(Cb + (size_t)l * DMODEL + tx * 4 + 64) = v1;
    }
}

extern "C" void kernel_launch(void* const* d_in, const int* in_sizes, int n_in,
                              void* d_out, int out_size, void* d_ws, size_t ws_size,
                              hipStream_t stream) {
    const float* hid        = (const float*)d_in[0];
    const float* W_in       = (const float*)d_in[1];
    const float* conv_w     = (const float*)d_in[2];
    const float* conv_b     = (const float*)d_in[3];
    const float* log_dt     = (const float*)d_in[4];
    const float* log_A_real = (const float*)d_in[5];
    const float* A_imag     = (const float*)d_in[6];
    const float* C_re       = (const float*)d_in[7];
    const float* C_im       = (const float*)d_in[8];
    const float* Dv         = (const float*)d_in[9];
    const float* W_out      = (const float*)d_in[10];
    float* out = (float*)d_out;
    float* ws  = (float*)d_ws;

    float* xz     = ws + WS_XZ;      // per-batch [2H][L]; y aliases x half
    float* coef   = ws + WS_COEF;
    float* states = ws + WS_STATES;
    float* look   = ws + WS_LOOK;

    coef_kernel<<<(H_DIM * N_ST + 255) / 256, 256, 0, stream>>>(
        log_dt, log_A_real, A_imag, C_re, C_im, coef);

    const int nscan = H_DIM * NC;  // 65536
    dim3 g1(L_SEQ / 128, 2 * H_DIM / 128);  // (32,32)
    dim3 g2(DMODEL / 128, L_SEQ / 128);     // (8,32)

    for (int b = 0; b < B_SZ; ++b) {
        const float* hid_b = hid + (size_t)b * L_SEQ * DMODEL;
        float* out_b = out + (size_t)b * L_SEQ * DMODEL;

        gemm_in<<<g1, 256, 0, stream>>>(hid_b, W_in, xz);
        scan_phase1<<<nscan / 256, 256, 0, stream>>>(xz, coef, conv_w, conv_b, states, look);
        scan_phase2<<<(H_DIM + 255) / 256, 256, 0, stream>>>(coef, states);
        scan_phase3<<<nscan / 256, 256, 0, stream>>>(xz, coef, conv_w, conv_b, Dv, states, look);
        gemm_out<<<g2, 256, 0, stream>>>(xz /*y aliases x*/, W_out, out_b);
    }
}

// Round 3
// 1689.298 us; speedup vs baseline: 1.8808x; 1.8808x over previous
//
#include <hip/hip_runtime.h>
#include <hip/hip_bf16.h>
#include <math.h>

#define H_DIM 2048
#define N_ST 8
#define B_SZ 4
#define L_SEQ 4096
#define DMODEL 1024
#define DCONV 4
#define CL 128
#define NC (L_SEQ / CL)   // 32

typedef __bf16 bf16x8 __attribute__((ext_vector_type(8)));
typedef __bf16 bf16x4 __attribute__((ext_vector_type(4)));
typedef float f32x4 __attribute__((ext_vector_type(4)));

typedef const unsigned int __attribute__((address_space(1)))* gptr_t;
typedef unsigned int __attribute__((address_space(3)))* lptr_t;

__device__ __forceinline__ void gl_lds16(const __bf16* g, __bf16* l) {
    __builtin_amdgcn_global_load_lds((gptr_t)g, (lptr_t)l, 16, 0, 0);
}

// -------- workspace layout (floats), total 28,672,000 f = 114.7 MB --------
// xz      : [2H][L] f32   @ 0           (x half -> y in place; z half reused as yT planes)
// yTh/yTl : [L][H] bf16   @ 8388608 / 12582912   (overlay z half, born after z dead)
// coef    : 6*[H][N]      @ 16777216
// states  : [H][NC][N][2] @ 16875520
// look    : [H][NC][4]    @ 17924096
// Hh/Hl   : [L][D] bf16   @ 18186240 / 20283392  (per batch)
// Wih/Wil : [2H][D] bf16  @ 22380544 / 24477696
// Woh/Wol : [DM][H] bf16  @ 26574848 / 27623424
#define WS_XZ     0
#define WS_YTH    8388608
#define WS_YTL    12582912
#define WS_COEF   16777216
#define WS_STATES 16875520
#define WS_LOOK   17924096
#define WS_HH     18186240
#define WS_HL     20283392
#define WS_WIH    22380544
#define WS_WIL    24477696
#define WS_WOH    26574848
#define WS_WOL    27623424

// ============ split f32 -> bf16 hi/lo planes ============
__global__ __launch_bounds__(256) void cvt_split4(const float* __restrict__ s,
                                                  __bf16* __restrict__ h,
                                                  __bf16* __restrict__ l, int n4) {
    int i = blockIdx.x * 256 + threadIdx.x;
    if (i >= n4) return;
    float4 v = ((const float4*)s)[i];
    float vv[4] = {v.x, v.y, v.z, v.w};
    bf16x4 hv, lv;
#pragma unroll
    for (int j = 0; j < 4; ++j) {
        __bf16 hb = (__bf16)vv[j];
        hv[j] = hb;
        lv[j] = (__bf16)(vv[j] - (float)hb);
    }
    *(bf16x4*)&h[(size_t)i * 4] = hv;
    *(bf16x4*)&l[(size_t)i * 4] = lv;
}

// ============ coefficient precompute ============
__global__ void coef_kernel(const float* __restrict__ log_dt,
                            const float* __restrict__ log_A_real,
                            const float* __restrict__ A_imag,
                            const float* __restrict__ C_re,
                            const float* __restrict__ C_im,
                            float* __restrict__ coef) {
    int i = blockIdx.x * blockDim.x + threadIdx.x;
    if (i >= H_DIM * N_ST) return;
    int h = i >> 3;
    float dt = expf(log_dt[h]);
    float Ar = -expf(log_A_real[i]);
    float Ai = A_imag[i];
    float er = expf(dt * Ar);
    float ang = dt * Ai;
    float wr = er * cosf(ang);
    float wi = er * sinf(ang);
    float den = Ar * Ar + Ai * Ai;
    float qr = ((wr - 1.f) * Ar + wi * Ai) / den;
    float qi = (wi * Ar - (wr - 1.f) * Ai) / den;
    float Cr = C_re[i], Ci = C_im[i];
    float Ctr = Cr * qr - Ci * qi;
    float Cti = Cr * qi + Ci * qr;
    float eCL = expf((float)CL * dt * Ar);
    float aCL = (float)CL * dt * Ai;
    float pr = eCL * cosf(aCL);
    float pi = eCL * sinf(aCL);
    const int HN = H_DIM * N_ST;
    coef[i]          = wr;
    coef[HN + i]     = wi;
    coef[2 * HN + i] = Ctr;
    coef[3 * HN + i] = Cti;
    coef[4 * HN + i] = pr;
    coef[5 * HN + i] = pi;
}

// ============ split-bf16 MFMA GEMM (B^T form) ============
// C[M][N] = sum_k A[m][k]*B[n][k], A,B given as bf16 hi/lo planes with row stride K.
// C = Ah*Bh + Ah*Bl + Al*Bh (fp32 accum). 128x128 tile, 4 waves (2x2), BK=32.
// LDS per plane: [4 kb][128 row][8 elem] bf16 (8KB) -> frag ds_read_b128 2-way only.
__global__ __launch_bounds__(256, 2) void gemm_split(const __bf16* __restrict__ Ah,
                                                     const __bf16* __restrict__ Al,
                                                     const __bf16* __restrict__ Bh,
                                                     const __bf16* __restrict__ Bl,
                                                     float* __restrict__ C,
                                                     int K, int ldc) {
    __shared__ __bf16 sAh[4096], sAl[4096], sBh[4096], sBl[4096];
    const int tid = threadIdx.x;
    const int lane = tid & 63;
    const int wid = tid >> 6;
    const int wr = wid >> 1, wc = wid & 1;
    const int bm = blockIdx.y, bn = blockIdx.x;

    const int r = tid & 127;       // staging row within tile
    const int kbq = tid >> 7;      // staging kb low bit
    const size_t arow = (size_t)(bm * 128 + r) * K;
    const size_t brow = (size_t)(bn * 128 + r) * K;

    f32x4 acc[4][4];
#pragma unroll
    for (int m = 0; m < 4; ++m)
#pragma unroll
        for (int n = 0; n < 4; ++n) acc[m][n] = (f32x4){0.f, 0.f, 0.f, 0.f};

    const int kb = lane >> 4, rr = lane & 15;

    for (int k0 = 0; k0 < K; k0 += 32) {
        __syncthreads();
#pragma unroll
        for (int q = 0; q < 2; ++q) {
            const int skb = q * 2 + kbq;              // global kb 0..3
            const int lo = q * 2048 + tid * 8;        // LDS elem offset (16B/lane)
            const size_t go = k0 + skb * 8;
            gl_lds16(Ah + arow + go, &sAh[lo]);
            gl_lds16(Al + arow + go, &sAl[lo]);
            gl_lds16(Bh + brow + go, &sBh[lo]);
            gl_lds16(Bl + brow + go, &sBl[lo]);
        }
        __syncthreads();

        bf16x8 fAh[4], fAl[4], fBh[4], fBl[4];
#pragma unroll
        for (int m = 0; m < 4; ++m) {
            int off = kb * 1024 + (wr * 64 + m * 16 + rr) * 8;
            fAh[m] = *(const bf16x8*)&sAh[off];
            fAl[m] = *(const bf16x8*)&sAl[off];
        }
#pragma unroll
        for (int n = 0; n < 4; ++n) {
            int off = kb * 1024 + (wc * 64 + n * 16 + rr) * 8;
            fBh[n] = *(const bf16x8*)&sBh[off];
            fBl[n] = *(const bf16x8*)&sBl[off];
        }
#pragma unroll
        for (int m = 0; m < 4; ++m)
#pragma unroll
            for (int n = 0; n < 4; ++n) {
                acc[m][n] = __builtin_amdgcn_mfma_f32_16x16x32_bf16(fAh[m], fBh[n], acc[m][n], 0, 0, 0);
                acc[m][n] = __builtin_amdgcn_mfma_f32_16x16x32_bf16(fAh[m], fBl[n], acc[m][n], 0, 0, 0);
                acc[m][n] = __builtin_amdgcn_mfma_f32_16x16x32_bf16(fAl[m], fBh[n], acc[m][n], 0, 0, 0);
            }
    }

    const int rq = lane >> 4;
#pragma unroll
    for (int m = 0; m < 4; ++m)
#pragma unroll
        for (int n = 0; n < 4; ++n) {
            int col = bn * 128 + wc * 64 + n * 16 + rr;
            int row0 = bm * 128 + wr * 64 + m * 16 + rq * 4;
#pragma unroll
            for (int j = 0; j < 4; ++j)
                C[(size_t)(row0 + j) * ldc + col] = acc[m][n][j];
        }
}

// ============ scan phase 1: local chunk scans (fused conv+SiLU) ============
__global__ __launch_bounds__(256) void scan_phase1(const float* __restrict__ xz,
                                                   const float* __restrict__ coef,
                                                   const float* __restrict__ conv_w,
                                                   const float* __restrict__ conv_b,
                                                   float* __restrict__ states,
                                                   float* __restrict__ look) {
    int t = blockIdx.x * 256 + threadIdx.x;   // t = h*NC + c
    int c = t & (NC - 1);
    int h = t >> 5;

    const int HN = H_DIM * N_ST;
    float wr[N_ST], wi[N_ST];
#pragma unroll
    for (int n = 0; n < N_ST; ++n) {
        wr[n] = coef[h * N_ST + n];
        wi[n] = coef[HN + h * N_ST + n];
    }
    float cw0 = conv_w[h * 4 + 0], cw1 = conv_w[h * 4 + 1];
    float cw2 = conv_w[h * 4 + 2], cw3 = conv_w[h * 4 + 3];
    float cb = conv_b[h];

    const float* xrow = xz + (size_t)h * L_SEQ + c * CL;
    float x3 = 0.f, x2 = 0.f, x1 = 0.f;
    if (c > 0) {
        float4 p = *(const float4*)(xrow - 4);
        x3 = p.y; x2 = p.z; x1 = p.w;
    }
    *(float4*)(look + (size_t)t * 4) = make_float4(x3, x2, x1, 0.f);

    float sr[N_ST], si[N_ST];
#pragma unroll
    for (int n = 0; n < N_ST; ++n) { sr[n] = 0.f; si[n] = 0.f; }

    for (int j = 0; j < CL; j += 4) {
        float4 v = *(const float4*)(xrow + j);
        float xv[4] = {v.x, v.y, v.z, v.w};
#pragma unroll
        for (int k = 0; k < 4; ++k) {
            float u = cw0 * x3 + cw1 * x2 + cw2 * x1 + cw3 * xv[k] + cb;
            float xc = u / (1.f + __expf(-u));
            x3 = x2; x2 = x1; x1 = xv[k];
#pragma unroll
            for (int n = 0; n < N_ST; ++n) {
                float nr = wr[n] * sr[n] - wi[n] * si[n] + xc;
                float ni = wr[n] * si[n] + wi[n] * sr[n];
                sr[n] = nr; si[n] = ni;
            }
        }
    }
    float* st = states + (size_t)t * (N_ST * 2);
#pragma unroll
    for (int n = 0; n < N_ST; ++n) { st[2 * n] = sr[n]; st[2 * n + 1] = si[n]; }
}

// ============ scan phase 2: combine chunk states -> chunk init states ============
__global__ __launch_bounds__(256) void scan_phase2(const float* __restrict__ coef,
                                                   float* __restrict__ states) {
    int h = blockIdx.x * 256 + threadIdx.x;
    if (h >= H_DIM) return;
    const int HN = H_DIM * N_ST;
    float pr[N_ST], pi[N_ST];
#pragma unroll
    for (int n = 0; n < N_ST; ++n) {
        pr[n] = coef[4 * HN + h * N_ST + n];
        pi[n] = coef[5 * HN + h * N_ST + n];
    }
    float sr[N_ST], si[N_ST];
#pragma unroll
    for (int n = 0; n < N_ST; ++n) { sr[n] = 0.f; si[n] = 0.f; }
    float* base = states + (size_t)h * NC * (N_ST * 2);
    for (int c = 0; c < NC; ++c) {
        float* st = base + c * (N_ST * 2);
#pragma unroll
        for (int n = 0; n < N_ST; ++n) {
            float lr = st[2 * n], li = st[2 * n + 1];
            st[2 * n] = sr[n]; st[2 * n + 1] = si[n];
            float nr = pr[n] * sr[n] - pi[n] * si[n] + lr;
            float ni = pr[n] * si[n] + pi[n] * sr[n] + li;
            sr[n] = nr; si[n] = ni;
        }
    }
}

// ============ scan phase 3: replay, fused D-skip + gate; writes y f32 OVER x ============
__global__ __launch_bounds__(256) void scan_phase3(float* __restrict__ xz,
                                                   const float* __restrict__ coef,
                                                   const float* __restrict__ conv_w,
                                                   const float* __restrict__ conv_b,
                                                   const float* __restrict__ Dvec,
                                                   const float* __restrict__ states,
                                                   const float* __restrict__ look) {
    int t = blockIdx.x * 256 + threadIdx.x;
    int c = t & (NC - 1);
    int h = t >> 5;

    const int HN = H_DIM * N_ST;
    float wr[N_ST], wi[N_ST], Ctr[N_ST], Cti[N_ST];
#pragma unroll
    for (int n = 0; n < N_ST; ++n) {
        wr[n]  = coef[h * N_ST + n];
        wi[n]  = coef[HN + h * N_ST + n];
        Ctr[n] = coef[2 * HN + h * N_ST + n];
        Cti[n] = coef[3 * HN + h * N_ST + n];
    }
    float cw0 = conv_w[h * 4 + 0], cw1 = conv_w[h * 4 + 1];
    float cw2 = conv_w[h * 4 + 2], cw3 = conv_w[h * 4 + 3];
    float cb = conv_b[h];
    float Dh = Dvec[h];

    float* xrow = xz + (size_t)h * L_SEQ + c * CL;
    const float* zrow = xz + (size_t)(H_DIM + h) * L_SEQ + c * CL;

    float4 lk = *(const float4*)(look + (size_t)t * 4);
    float x3 = lk.x, x2 = lk.y, x1 = lk.z;

    const float* st = states + (size_t)t * (N_ST * 2);
    float sr[N_ST], si[N_ST];
#pragma unroll
    for (int n = 0; n < N_ST; ++n) { sr[n] = st[2 * n]; si[n] = st[2 * n + 1]; }

    for (int j = 0; j < CL; j += 4) {
        float4 v = *(const float4*)(xrow + j);
        float4 zv = *(const float4*)(zrow + j);
        float xv[4] = {v.x, v.y, v.z, v.w};
        float zz[4] = {zv.x, zv.y, zv.z, zv.w};
        float out[4];
#pragma unroll
        for (int k = 0; k < 4; ++k) {
            float u = cw0 * x3 + cw1 * x2 + cw2 * x1 + cw3 * xv[k] + cb;
            float xc = u / (1.f + __expf(-u));
            x3 = x2; x2 = x1; x1 = xv[k];
            float accy = 0.f;
#pragma unroll
            for (int n = 0; n < N_ST; ++n) {
                float nr = wr[n] * sr[n] - wi[n] * si[n] + xc;
                float ni = wr[n] * si[n] + wi[n] * sr[n];
                sr[n] = nr; si[n] = ni;
                accy += Ctr[n] * nr - Cti[n] * ni;
            }
            float yv = 2.f * accy + Dh * xc;
            float g = zz[k] / (1.f + __expf(-zz[k]));
            out[k] = yv * g;
        }
        *(float4*)(xrow + j) = make_float4(out[0], out[1], out[2], out[3]);
    }
}

// ============ transpose + split: y f32 [H][L] -> yTh/yTl bf16 [L][H] ============
// 64x64 tiles; writes land in the (dead) z half of xz.
__global__ __launch_bounds__(256) void transpose_split(const float* __restrict__ y,
                                                       __bf16* __restrict__ th,
                                                       __bf16* __restrict__ tl) {
    __shared__ float tile[64][65];
    const int l0 = blockIdx.x * 64, h0 = blockIdx.y * 64;
    const int tid = threadIdx.x;
    const int r = tid >> 4, c4 = (tid & 15) * 4;
#pragma unroll
    for (int p = 0; p < 4; ++p) {
        float4 v = *(const float4*)(y + (size_t)(h0 + r + p * 16) * L_SEQ + l0 + c4);
        tile[r + p * 16][c4 + 0] = v.x;
        tile[r + p * 16][c4 + 1] = v.y;
        tile[r + p * 16][c4 + 2] = v.z;
        tile[r + p * 16][c4 + 3] = v.w;
    }
    __syncthreads();
    const int l = tid >> 2, hb = (tid & 3) * 16;
    float vals[16];
#pragma unroll
    for (int j = 0; j < 16; ++j) vals[j] = tile[hb + j][l];
    bf16x8 hv0, hv1, lv0, lv1;
#pragma unroll
    for (int j = 0; j < 8; ++j) {
        __bf16 hbv = (__bf16)vals[j];
        hv0[j] = hbv;
        lv0[j] = (__bf16)(vals[j] - (float)hbv);
        __bf16 hbv2 = (__bf16)vals[j + 8];
        hv1[j] = hbv2;
        lv1[j] = (__bf16)(vals[j + 8] - (float)hbv2);
    }
    size_t base = (size_t)(l0 + l) * H_DIM + h0 + hb;
    *(bf16x8*)&th[base] = hv0;
    *(bf16x8*)&th[base + 8] = hv1;
    *(bf16x8*)&tl[base] = lv0;
    *(bf16x8*)&tl[base + 8] = lv1;
}

extern "C" void kernel_launch(void* const* d_in, const int* in_sizes, int n_in,
                              void* d_out, int out_size, void* d_ws, size_t ws_size,
                              hipStream_t stream) {
    const float* hid        = (const float*)d_in[0];
    const float* W_in       = (const float*)d_in[1];
    const float* conv_w     = (const float*)d_in[2];
    const float* conv_b     = (const float*)d_in[3];
    const float* log_dt     = (const float*)d_in[4];
    const float* log_A_real = (const float*)d_in[5];
    const float* A_imag     = (const float*)d_in[6];
    const float* C_re       = (const float*)d_in[7];
    const float* C_im       = (const float*)d_in[8];
    const float* Dv         = (const float*)d_in[9];
    const float* W_out      = (const float*)d_in[10];
    float* out = (float*)d_out;
    float* ws  = (float*)d_ws;

    float* xz      = ws + WS_XZ;
    __bf16* yTh    = (__bf16*)(ws + WS_YTH);
    __bf16* yTl    = (__bf16*)(ws + WS_YTL);
    float* coef    = ws + WS_COEF;
    float* states  = ws + WS_STATES;
    float* look    = ws + WS_LOOK;
    __bf16* Hh     = (__bf16*)(ws + WS_HH);
    __bf16* Hl     = (__bf16*)(ws + WS_HL);
    __bf16* Wih    = (__bf16*)(ws + WS_WIH);
    __bf16* Wil    = (__bf16*)(ws + WS_WIL);
    __bf16* Woh    = (__bf16*)(ws + WS_WOH);
    __bf16* Wol    = (__bf16*)(ws + WS_WOL);

    coef_kernel<<<(H_DIM * N_ST + 255) / 256, 256, 0, stream>>>(
        log_dt, log_A_real, A_imag, C_re, C_im, coef);

    // weight splits (once per call)
    cvt_split4<<<(2 * H_DIM * DMODEL / 4 + 255) / 256, 256, 0, stream>>>(W_in, Wih, Wil, 2 * H_DIM * DMODEL / 4);
    cvt_split4<<<(DMODEL * H_DIM / 4 + 255) / 256, 256, 0, stream>>>(W_out, Woh, Wol, DMODEL * H_DIM / 4);

    const int nscan = H_DIM * NC;            // 65536
    dim3 gIn(L_SEQ / 128, 2 * H_DIM / 128);  // (32,32)
    dim3 gOut(DMODEL / 128, L_SEQ / 128);    // (8,32)
    dim3 gTr(L_SEQ / 64, H_DIM / 64);        // (64,32)

    for (int b = 0; b < B_SZ; ++b) {
        const float* hid_b = hid + (size_t)b * L_SEQ * DMODEL;
        float* out_b = out + (size_t)b * L_SEQ * DMODEL;

        cvt_split4<<<(L_SEQ * DMODEL / 4 + 255) / 256, 256, 0, stream>>>(hid_b, Hh, Hl, L_SEQ * DMODEL / 4);
        gemm_split<<<gIn, 256, 0, stream>>>(Wih, Wil, Hh, Hl, xz, DMODEL, L_SEQ);
        scan_phase1<<<nscan / 256, 256, 0, stream>>>(xz, coef, conv_w, conv_b, states, look);
        scan_phase2<<<(H_DIM + 255) / 256, 256, 0, stream>>>(coef, states);
        scan_phase3<<<nscan / 256, 256, 0, stream>>>(xz, coef, conv_w, conv_b, Dv, states, look);
        transpose_split<<<gTr, 256, 0, stream>>>(xz, yTh, yTl);
        gemm_split<<<gOut, 256, 0, stream>>>(yTh, yTl, Woh, Wol, out_b, H_DIM, DMODEL);
    }
}